// Round 4
// baseline (752.725 us; speedup 1.0000x reference)
//
#include <hip/hip_runtime.h>

#define N_NODES_C 100000
#define N_EDGES_C 1200000
#define NUM_GRAPHS_C 64
#define D_C 64
#define BN_EPS_C 1e-5f

typedef unsigned short u16;
typedef unsigned int u32;

__device__ __forceinline__ u16 f2bf(float f) {  // RTNE
    u32 x = __float_as_uint(f);
    x += 0x7fffu + ((x >> 16) & 1u);
    return (u16)(x >> 16);
}

// ----------------------------- degree count ------------------------------
__global__ void k_deg(const int* __restrict__ dst, int* __restrict__ deg) {
    int e = blockIdx.x * blockDim.x + threadIdx.x;
    if (e < N_EDGES_C) atomicAdd(&deg[dst[e]], 1);
}

// ----------------------------- scan (3 phase) ----------------------------
__global__ void k_scan_a(const int* __restrict__ deg, int* __restrict__ bsum) {
    int t = threadIdx.x;
    int i0 = blockIdx.x * 1024 + t * 4;
    int s = 0;
#pragma unroll
    for (int k = 0; k < 4; ++k) { int i = i0 + k; if (i < N_NODES_C) s += deg[i]; }
    __shared__ int sm[256];
    sm[t] = s; __syncthreads();
    for (int off = 128; off > 0; off >>= 1) {
        if (t < off) sm[t] += sm[t + off];
        __syncthreads();
    }
    if (t == 0) bsum[blockIdx.x] = sm[0];
}

__global__ void k_scan_b(const int* __restrict__ bsum, int* __restrict__ bscan, int nb) {
    int t = threadIdx.x;
    __shared__ int sm[128];
    int v = (t < nb) ? bsum[t] : 0;
    sm[t] = v; __syncthreads();
    for (int off = 1; off < 128; off <<= 1) {
        int x = (t >= off) ? sm[t - off] : 0;
        __syncthreads();
        sm[t] += x;
        __syncthreads();
    }
    if (t < nb) bscan[t] = sm[t] - v;  // exclusive
}

__global__ void k_scan_c(const int* __restrict__ deg, const int* __restrict__ bscan,
                         int* __restrict__ rowptr, int* __restrict__ cursor,
                         float* __restrict__ dinv) {
    int t = threadIdx.x;
    int i0 = blockIdx.x * 1024 + t * 4;
    int d[4]; int s = 0;
#pragma unroll
    for (int k = 0; k < 4; ++k) { int i = i0 + k; d[k] = (i < N_NODES_C) ? deg[i] : 0; s += d[k]; }
    __shared__ int sm[256];
    sm[t] = s; __syncthreads();
    for (int off = 1; off < 256; off <<= 1) {
        int x = (t >= off) ? sm[t - off] : 0;
        __syncthreads();
        sm[t] += x;
        __syncthreads();
    }
    int ex = sm[t] - s + bscan[blockIdx.x];
#pragma unroll
    for (int k = 0; k < 4; ++k) {
        int i = i0 + k;
        if (i < N_NODES_C) {
            rowptr[i] = ex;
            cursor[i] = ex;
            dinv[i] = rsqrtf((float)(d[k] + 1));  // +1 self-loop
            ex += d[k];
        }
    }
    if (blockIdx.x == 0 && t == 0) rowptr[N_NODES_C] = N_EDGES_C;
}

// ----------------------------- scatter to CSR ----------------------------
__global__ void k_scatter(const int* __restrict__ src, const int* __restrict__ dst,
                          int* __restrict__ cursor, const float* __restrict__ dinv,
                          int2* __restrict__ colw) {
    int e = blockIdx.x * blockDim.x + threadIdx.x;
    if (e < N_EDGES_C) {
        int s = src[e], d = dst[e];
        int pos = atomicAdd(&cursor[d], 1);
        float w = dinv[s] * dinv[d];
        colw[pos] = make_int2(s, __float_as_int(w));
    }
}

// ----------------------------- GEMM [N,64]x[64,64] -> bf16 ----------------
// __launch_bounds__(256,4): VGPR cap 128 so Wc[64] stays in registers
// (previous build spilled at VGPR_Count=56). 8 rows/iter = 8 FMA chains.
__global__ void __launch_bounds__(256, 4) k_gemm64(
        const float* __restrict__ X, const float* __restrict__ W,
        u16* __restrict__ T) {
    int lane = threadIdx.x & 63;
    int wave = blockIdx.x * 4 + (threadIdx.x >> 6);
    int nwaves = gridDim.x * 4;
    float Wc[64];
#pragma unroll
    for (int k = 0; k < 64; ++k) Wc[k] = W[k * 64 + lane];
    const float4* X4 = (const float4*)X;
    for (int r0 = wave * 8; r0 < N_NODES_C; r0 += nwaves * 8) {
        float acc[8];
#pragma unroll
        for (int rr = 0; rr < 8; ++rr) acc[rr] = 0.f;
#pragma unroll
        for (int kq = 0; kq < 16; ++kq) {
            float4 q[8];
#pragma unroll
            for (int rr = 0; rr < 8; ++rr) q[rr] = X4[(size_t)(r0 + rr) * 16 + kq];
#pragma unroll
            for (int rr = 0; rr < 8; ++rr) {
                acc[rr] = fmaf(q[rr].x, Wc[4 * kq + 0], acc[rr]);
                acc[rr] = fmaf(q[rr].y, Wc[4 * kq + 1], acc[rr]);
                acc[rr] = fmaf(q[rr].z, Wc[4 * kq + 2], acc[rr]);
                acc[rr] = fmaf(q[rr].w, Wc[4 * kq + 3], acc[rr]);
            }
        }
#pragma unroll
        for (int rr = 0; rr < 8; ++rr)
            T[(size_t)(r0 + rr) * 64 + lane] = f2bf(acc[rr]);
    }
}

// ----------------------------- gather (split-wave pair) -------------------
// Persistent waves over node PAIRS. Wave split into two 32-lane halves; each
// lane covers 2 features (ushort2). Half 0 takes edges j..j+7, half 1 takes
// j+8..j+15 -> one T-load instruction serves 2 edges; serial batch count
// halves. cndmask routes each edge into accA/accB; cross-half shfl_xor(32)
// combine; half 0 writes/pools node rA, half 1 node rB.
template <bool POOL>
__device__ __forceinline__ void gather_body(
        const u16* __restrict__ T, const int2* __restrict__ colw,
        const int* __restrict__ rowptr, const float* __restrict__ dinv,
        const float* __restrict__ b, const float* __restrict__ g,
        const float* __restrict__ be, const float* __restrict__ m,
        const float* __restrict__ v, const int* __restrict__ batch,
        float* __restrict__ A, float* __restrict__ pooled) {
    int lane = threadIdx.x & 63;
    int half = (lane >> 5) & 1;
    int f0 = (lane & 31) * 2;
    int wave = blockIdx.x * 4 + (threadIdx.x >> 6);
    int nwaves = gridDim.x * 4;
    float sc0 = g[f0] * rsqrtf(v[f0] + BN_EPS_C);
    float c00 = (b[f0] - m[f0]) * sc0 + be[f0];
    float sc1 = g[f0 + 1] * rsqrtf(v[f0 + 1] + BN_EPS_C);
    float c01 = (b[f0 + 1] - m[f0 + 1]) * sc1 + be[f0 + 1];
    const int npairs = N_NODES_C / 2;
    for (int base = wave; base < npairs; base += nwaves) {
        int rA = __builtin_amdgcn_readfirstlane(base * 2);
        int rB = rA + 1;
        int jbA = rowptr[rA], jeA = rowptr[rB], jeB = rowptr[rB + 1];
        float drA = dinv[rA], drB = dinv[rB];
        int rself = half ? rB : rA;
        float dself = half ? drB : drA;
        u32 tself = *(const u32*)(T + (size_t)rself * 64 + f0);
        float s0 = __uint_as_float(tself << 16) * dself * dself;
        float s1 = __uint_as_float(tself & 0xffff0000u) * dself * dself;
        float accA0 = half ? 0.f : s0, accA1 = half ? 0.f : s1;
        float accB0 = half ? s0 : 0.f, accB1 = half ? s1 : 0.f;
        for (int j = jbA; j < jeB; j += 16) {
            int j0 = j + half * 8;
            int idx[8]; float wA[8], wB[8];
#pragma unroll
            for (int k = 0; k < 8; ++k) {
                int jj = j0 + k;
                bool valid = jj < jeB;
                int2 e = colw[valid ? jj : jbA];
                float w = valid ? __int_as_float(e.y) : 0.f;
                bool isB = jj >= jeA;
                wA[k] = isB ? 0.f : w;
                wB[k] = isB ? w : 0.f;
                idx[k] = e.x;
            }
            u32 tv[8];
#pragma unroll
            for (int k = 0; k < 8; ++k)
                tv[k] = *(const u32*)(T + (size_t)idx[k] * 64 + f0);
#pragma unroll
            for (int k = 0; k < 8; ++k) {
                float t0 = __uint_as_float(tv[k] << 16);
                float t1 = __uint_as_float(tv[k] & 0xffff0000u);
                accA0 = fmaf(t0, wA[k], accA0);
                accA1 = fmaf(t1, wA[k], accA1);
                accB0 = fmaf(t0, wB[k], accB0);
                accB1 = fmaf(t1, wB[k], accB1);
            }
        }
        accA0 += __shfl_xor(accA0, 32, 64);
        accA1 += __shfl_xor(accA1, 32, 64);
        accB0 += __shfl_xor(accB0, 32, 64);
        accB1 += __shfl_xor(accB1, 32, 64);
        float o0 = half ? accB0 : accA0;
        float o1 = half ? accB1 : accA1;
        float val0 = fmaxf(fmaf(o0, sc0, c00), 0.f);
        float val1 = fmaxf(fmaf(o1, sc1, c01), 0.f);
        int r = half ? rB : rA;
        if (POOL) {
            int gid = batch[r];
            atomicAdd(&pooled[gid * 64 + f0], val0);
            atomicAdd(&pooled[gid * 64 + f0 + 1], val1);
        } else {
            *(float2*)(A + (size_t)r * 64 + f0) = make_float2(val0, val1);
        }
    }
}

__global__ void __launch_bounds__(256) k_gather1(
        const u16* __restrict__ T, const int2* __restrict__ colw,
        const int* __restrict__ rowptr, const float* __restrict__ dinv,
        const float* __restrict__ b, const float* __restrict__ g,
        const float* __restrict__ be, const float* __restrict__ m,
        const float* __restrict__ v, float* __restrict__ A) {
    gather_body<false>(T, colw, rowptr, dinv, b, g, be, m, v, nullptr, A, nullptr);
}

__global__ void __launch_bounds__(256) k_gather2(
        const u16* __restrict__ T, const int2* __restrict__ colw,
        const int* __restrict__ rowptr, const float* __restrict__ dinv,
        const float* __restrict__ b, const float* __restrict__ g,
        const float* __restrict__ be, const float* __restrict__ m,
        const float* __restrict__ v, const int* __restrict__ batch,
        float* __restrict__ pooled) {
    gather_body<true>(T, colw, rowptr, dinv, b, g, be, m, v, batch, nullptr, pooled);
}

// ----------------------------- classifier --------------------------------
__global__ void k_final(const float* __restrict__ pooled, const int* __restrict__ batch,
                        const float* __restrict__ Wc, const float* __restrict__ bc,
                        float* __restrict__ out) {
    __shared__ float sp[64 * 65];
    __shared__ int sub[64];
    int t = threadIdx.x;  // 256 threads
    for (int i = t; i < 4096; i += 256) sp[(i >> 6) * 65 + (i & 63)] = pooled[i];
    if (t < 64) {
        int lo = 0, hi = N_NODES_C;
        while (lo < hi) { int mid = (lo + hi) >> 1; if (batch[mid] > t) hi = mid; else lo = mid + 1; }
        sub[t] = lo;  // first index with batch > t
    }
    __syncthreads();
    if (t < 64) {
        int gi = t;
        int lb = gi ? sub[gi - 1] : 0;
        int cnt = sub[gi] - lb;
        float inv = 1.0f / fmaxf((float)cnt, 1.0f);
        float a0 = 0.f, a1 = 0.f;
#pragma unroll 8
        for (int f = 0; f < 64; ++f) {
            float p = sp[gi * 65 + f];
            a0 = fmaf(p, Wc[f * 2 + 0], a0);
            a1 = fmaf(p, Wc[f * 2 + 1], a1);
        }
        out[gi * 2 + 0] = a0 * inv + bc[0];
        out[gi * 2 + 1] = a1 * inv + bc[1];
    }
}

extern "C" void kernel_launch(void* const* d_in, const int* in_sizes, int n_in,
                              void* d_out, int out_size, void* d_ws, size_t ws_size,
                              hipStream_t stream) {
    const float* x    = (const float*)d_in[0];
    const int*   ei   = (const int*)d_in[1];
    const int*   batch= (const int*)d_in[2];
    const float* W1 = (const float*)d_in[3];
    const float* b1 = (const float*)d_in[4];
    const float* g1 = (const float*)d_in[5];
    const float* be1= (const float*)d_in[6];
    const float* m1 = (const float*)d_in[7];
    const float* v1 = (const float*)d_in[8];
    const float* W2 = (const float*)d_in[9];
    const float* b2 = (const float*)d_in[10];
    const float* g2 = (const float*)d_in[11];
    const float* be2= (const float*)d_in[12];
    const float* m2 = (const float*)d_in[13];
    const float* v2 = (const float*)d_in[14];
    const float* Wc = (const float*)d_in[15];
    const float* bc = (const float*)d_in[16];
    float* out = (float*)d_out;

    char* ws = (char*)d_ws;
    size_t off = 0;
    auto alloc = [&](size_t bytes) {
        size_t o = off;
        off = (off + bytes + 511) & ~(size_t)511;
        return o;
    };
    size_t o_deg   = alloc((size_t)N_NODES_C * 4);
    size_t o_pool  = alloc((size_t)NUM_GRAPHS_C * D_C * 4);
    size_t zero_bytes = off;  // [deg | pooled] zeroed each call
    size_t o_rowptr= alloc((size_t)(N_NODES_C + 1) * 4);
    size_t o_cur   = alloc((size_t)N_NODES_C * 4);
    size_t o_dinv  = alloc((size_t)N_NODES_C * 4);
    size_t o_bsum  = alloc(128 * 4);
    size_t o_bscan = alloc(128 * 4);
    size_t o_colw  = alloc((size_t)N_EDGES_C * 8);
    size_t o_t     = alloc((size_t)N_NODES_C * D_C * 2);  // bf16
    size_t o_a     = alloc((size_t)N_NODES_C * D_C * 4);
    (void)ws_size; (void)in_sizes; (void)n_in; (void)out_size;

    int*   deg    = (int*)(ws + o_deg);
    float* pooled = (float*)(ws + o_pool);
    int*   rowptr = (int*)(ws + o_rowptr);
    int*   cursor = (int*)(ws + o_cur);
    float* dinv   = (float*)(ws + o_dinv);
    int*   bsum   = (int*)(ws + o_bsum);
    int*   bscan  = (int*)(ws + o_bscan);
    int2*  colw   = (int2*)(ws + o_colw);
    u16*   T      = (u16*)(ws + o_t);
    float* A      = (float*)(ws + o_a);

    const int* srcp = ei;
    const int* dstp = ei + N_EDGES_C;

    hipMemsetAsync(ws, 0, zero_bytes, stream);

    int eblocks = (N_EDGES_C + 255) / 256;
    int nb = (N_NODES_C + 1023) / 1024;  // 98
    int gblocks = 2048;  // 8192 persistent waves
    k_deg<<<eblocks, 256, 0, stream>>>(dstp, deg);
    k_scan_a<<<nb, 256, 0, stream>>>(deg, bsum);
    k_scan_b<<<1, 128, 0, stream>>>(bsum, bscan, nb);
    k_scan_c<<<nb, 256, 0, stream>>>(deg, bscan, rowptr, cursor, dinv);
    k_scatter<<<eblocks, 256, 0, stream>>>(srcp, dstp, cursor, dinv, colw);

    k_gemm64<<<1024, 256, 0, stream>>>(x, W1, T);
    k_gather1<<<gblocks, 256, 0, stream>>>(T, colw, rowptr, dinv, b1, g1, be1, m1, v1, A);
    k_gemm64<<<1024, 256, 0, stream>>>(A, W2, T);
    k_gather2<<<gblocks, 256, 0, stream>>>(T, colw, rowptr, dinv, b2, g2, be2, m2, v2,
                                           batch, pooled);
    k_final<<<1, 256, 0, stream>>>(pooled, batch, Wc, bc, out);
}

// Round 5
// 494.484 us; speedup vs baseline: 1.5222x; 1.5222x over previous
//
#include <hip/hip_runtime.h>

#define N_NODES_C 100000
#define N_EDGES_C 1200000
#define NUM_GRAPHS_C 64
#define D_C 64
#define BN_EPS_C 1e-5f

typedef unsigned short u16;
typedef unsigned int u32;

__device__ __forceinline__ u16 f2bf(float f) {  // RTNE
    u32 x = __float_as_uint(f);
    x += 0x7fffu + ((x >> 16) & 1u);
    return (u16)(x >> 16);
}
__device__ __forceinline__ float bf2f(u16 u) {
    return __uint_as_float(((u32)u) << 16);
}

// ----------------------------- degree count ------------------------------
__global__ void k_deg(const int* __restrict__ dst, int* __restrict__ deg) {
    int e = blockIdx.x * blockDim.x + threadIdx.x;
    if (e < N_EDGES_C) atomicAdd(&deg[dst[e]], 1);
}

// ----------------------------- scan (3 phase) ----------------------------
__global__ void k_scan_a(const int* __restrict__ deg, int* __restrict__ bsum) {
    int t = threadIdx.x;
    int i0 = blockIdx.x * 1024 + t * 4;
    int s = 0;
#pragma unroll
    for (int k = 0; k < 4; ++k) { int i = i0 + k; if (i < N_NODES_C) s += deg[i]; }
    __shared__ int sm[256];
    sm[t] = s; __syncthreads();
    for (int off = 128; off > 0; off >>= 1) {
        if (t < off) sm[t] += sm[t + off];
        __syncthreads();
    }
    if (t == 0) bsum[blockIdx.x] = sm[0];
}

__global__ void k_scan_b(const int* __restrict__ bsum, int* __restrict__ bscan, int nb) {
    int t = threadIdx.x;
    __shared__ int sm[128];
    int v = (t < nb) ? bsum[t] : 0;
    sm[t] = v; __syncthreads();
    for (int off = 1; off < 128; off <<= 1) {
        int x = (t >= off) ? sm[t - off] : 0;
        __syncthreads();
        sm[t] += x;
        __syncthreads();
    }
    if (t < nb) bscan[t] = sm[t] - v;  // exclusive
}

__global__ void k_scan_c(const int* __restrict__ deg, const int* __restrict__ bscan,
                         int* __restrict__ rowptr, int* __restrict__ cursor,
                         float* __restrict__ dinv) {
    int t = threadIdx.x;
    int i0 = blockIdx.x * 1024 + t * 4;
    int d[4]; int s = 0;
#pragma unroll
    for (int k = 0; k < 4; ++k) { int i = i0 + k; d[k] = (i < N_NODES_C) ? deg[i] : 0; s += d[k]; }
    __shared__ int sm[256];
    sm[t] = s; __syncthreads();
    for (int off = 1; off < 256; off <<= 1) {
        int x = (t >= off) ? sm[t - off] : 0;
        __syncthreads();
        sm[t] += x;
        __syncthreads();
    }
    int ex = sm[t] - s + bscan[blockIdx.x];
#pragma unroll
    for (int k = 0; k < 4; ++k) {
        int i = i0 + k;
        if (i < N_NODES_C) {
            rowptr[i] = ex;
            cursor[i] = ex;
            dinv[i] = rsqrtf((float)(d[k] + 1));  // +1 self-loop
            ex += d[k];
        }
    }
    if (blockIdx.x == 0 && t == 0) rowptr[N_NODES_C] = N_EDGES_C;
}

// ----------------------------- scatter to CSR ----------------------------
__global__ void k_scatter(const int* __restrict__ src, const int* __restrict__ dst,
                          int* __restrict__ cursor, const float* __restrict__ dinv,
                          int2* __restrict__ colw) {
    int e = blockIdx.x * blockDim.x + threadIdx.x;
    if (e < N_EDGES_C) {
        int s = src[e], d = dst[e];
        int pos = atomicAdd(&cursor[d], 1);
        float w = dinv[s] * dinv[d];
        colw[pos] = make_int2(s, __float_as_int(w));
    }
}

// ----------------------------- GEMM [N,64]x[64,64] -> bf16 ----------------
// W staged in LDS (16 KB). Lesson from R3/R4: the compiler will NOT keep a
// per-lane float[64] array in VGPRs (spills to scratch at VGPR_Count=56);
// LDS reads Ws[k*64+lane] are lane-consecutive (32 banks x 2 lanes = free)
// and shared across the 4-row accumulator block. ~30 VGPRs, no spill.
__global__ void __launch_bounds__(256) k_gemm64(
        const float* __restrict__ X, const float* __restrict__ W,
        u16* __restrict__ T) {
    __shared__ float Ws[4096];
    int t = threadIdx.x;
    {
        const float4* W4 = (const float4*)W;
        float4* Ws4 = (float4*)Ws;
#pragma unroll
        for (int i = 0; i < 4; ++i) Ws4[t + 256 * i] = W4[t + 256 * i];
    }
    __syncthreads();
    int lane = t & 63;
    int wave = blockIdx.x * 4 + (t >> 6);
    int nwaves = gridDim.x * 4;
    const float4* X4 = (const float4*)X;
    const int nquads = N_NODES_C / 4;
    for (int q0 = wave; q0 < nquads; q0 += nwaves) {
        int r0 = q0 * 4;
        float a0 = 0.f, a1 = 0.f, a2 = 0.f, a3 = 0.f;
#pragma unroll
        for (int kq = 0; kq < 16; ++kq) {
            float4 x0 = X4[(size_t)(r0 + 0) * 16 + kq];
            float4 x1 = X4[(size_t)(r0 + 1) * 16 + kq];
            float4 x2 = X4[(size_t)(r0 + 2) * 16 + kq];
            float4 x3 = X4[(size_t)(r0 + 3) * 16 + kq];
            float w0 = Ws[(4 * kq + 0) * 64 + lane];
            float w1 = Ws[(4 * kq + 1) * 64 + lane];
            float w2 = Ws[(4 * kq + 2) * 64 + lane];
            float w3 = Ws[(4 * kq + 3) * 64 + lane];
            a0 = fmaf(x0.x, w0, a0); a0 = fmaf(x0.y, w1, a0);
            a0 = fmaf(x0.z, w2, a0); a0 = fmaf(x0.w, w3, a0);
            a1 = fmaf(x1.x, w0, a1); a1 = fmaf(x1.y, w1, a1);
            a1 = fmaf(x1.z, w2, a1); a1 = fmaf(x1.w, w3, a1);
            a2 = fmaf(x2.x, w0, a2); a2 = fmaf(x2.y, w1, a2);
            a2 = fmaf(x2.z, w2, a2); a2 = fmaf(x2.w, w3, a2);
            a3 = fmaf(x3.x, w0, a3); a3 = fmaf(x3.y, w1, a3);
            a3 = fmaf(x3.z, w2, a3); a3 = fmaf(x3.w, w3, a3);
        }
        T[(size_t)(r0 + 0) * 64 + lane] = f2bf(a0);
        T[(size_t)(r0 + 1) * 64 + lane] = f2bf(a1);
        T[(size_t)(r0 + 2) * 64 + lane] = f2bf(a2);
        T[(size_t)(r0 + 3) * 64 + lane] = f2bf(a3);
    }
}

// ----------------------------- gather (fused pair, R3-proven) -------------
// Persistent waves, grid-stride over node PAIRS (2r, 2r+1). CSR ranges of a
// pair are contiguous, so one flat 8-edge-batch loop feeds both accumulators
// via cndmask routing. LAYER2: fused mean-pool atomics (POOL=true).
template <bool POOL>
__device__ __forceinline__ void gather_body(
        const u16* __restrict__ T, const int2* __restrict__ colw,
        const int* __restrict__ rowptr, const float* __restrict__ dinv,
        const float* __restrict__ b, const float* __restrict__ g,
        const float* __restrict__ be, const float* __restrict__ m,
        const float* __restrict__ v, const int* __restrict__ batch,
        float* __restrict__ A, float* __restrict__ pooled) {
    int lane = threadIdx.x & 63;
    int wave = blockIdx.x * 4 + (threadIdx.x >> 6);
    int nwaves = gridDim.x * 4;
    float sc = g[lane] * rsqrtf(v[lane] + BN_EPS_C);
    float c0 = (b[lane] - m[lane]) * sc + be[lane];
    const int npairs = N_NODES_C / 2;
    for (int base = wave; base < npairs; base += nwaves) {
        int rA = __builtin_amdgcn_readfirstlane(base * 2);
        int rB = rA + 1;
        int jbA = rowptr[rA];
        int jeA = rowptr[rB];
        int jeB = rowptr[rB + 1];
        float drA = dinv[rA], drB = dinv[rB];
        float accA = bf2f(T[(size_t)rA * 64 + lane]) * drA * drA;  // self-loops
        float accB = bf2f(T[(size_t)rB * 64 + lane]) * drB * drB;
        for (int j = jbA; j < jeB; j += 8) {
            int idx[8]; float wA[8], wB[8];
#pragma unroll
            for (int k = 0; k < 8; ++k) {
                int jj = (j + k < jeB) ? (j + k) : jbA;
                int2 e = colw[jj];
                float w = (j + k < jeB) ? __int_as_float(e.y) : 0.f;
                bool isB = (j + k >= jeA);
                wA[k] = isB ? 0.f : w;
                wB[k] = isB ? w : 0.f;
                idx[k] = e.x;
            }
            float t[8];
#pragma unroll
            for (int k = 0; k < 8; ++k) t[k] = bf2f(T[(size_t)idx[k] * 64 + lane]);
#pragma unroll
            for (int k = 0; k < 8; ++k) {
                accA = fmaf(t[k], wA[k], accA);
                accB = fmaf(t[k], wB[k], accB);
            }
        }
        float valA = fmaxf(fmaf(accA, sc, c0), 0.f);
        float valB = fmaxf(fmaf(accB, sc, c0), 0.f);
        if (POOL) {
            int gA = batch[rA], gB = batch[rB];
            if (gA == gB) {
                atomicAdd(&pooled[gA * 64 + lane], valA + valB);
            } else {
                atomicAdd(&pooled[gA * 64 + lane], valA);
                atomicAdd(&pooled[gB * 64 + lane], valB);
            }
        } else {
            A[(size_t)rA * 64 + lane] = valA;
            A[(size_t)rB * 64 + lane] = valB;
        }
    }
}

__global__ void __launch_bounds__(256) k_gather1(
        const u16* __restrict__ T, const int2* __restrict__ colw,
        const int* __restrict__ rowptr, const float* __restrict__ dinv,
        const float* __restrict__ b, const float* __restrict__ g,
        const float* __restrict__ be, const float* __restrict__ m,
        const float* __restrict__ v, float* __restrict__ A) {
    gather_body<false>(T, colw, rowptr, dinv, b, g, be, m, v, nullptr, A, nullptr);
}

__global__ void __launch_bounds__(256) k_gather2(
        const u16* __restrict__ T, const int2* __restrict__ colw,
        const int* __restrict__ rowptr, const float* __restrict__ dinv,
        const float* __restrict__ b, const float* __restrict__ g,
        const float* __restrict__ be, const float* __restrict__ m,
        const float* __restrict__ v, const int* __restrict__ batch,
        float* __restrict__ pooled) {
    gather_body<true>(T, colw, rowptr, dinv, b, g, be, m, v, batch, nullptr, pooled);
}

// ----------------------------- classifier --------------------------------
__global__ void k_final(const float* __restrict__ pooled, const int* __restrict__ batch,
                        const float* __restrict__ Wc, const float* __restrict__ bc,
                        float* __restrict__ out) {
    __shared__ float sp[64 * 65];
    __shared__ int sub[64];
    int t = threadIdx.x;  // 256 threads
    for (int i = t; i < 4096; i += 256) sp[(i >> 6) * 65 + (i & 63)] = pooled[i];
    if (t < 64) {
        int lo = 0, hi = N_NODES_C;
        while (lo < hi) { int mid = (lo + hi) >> 1; if (batch[mid] > t) hi = mid; else lo = mid + 1; }
        sub[t] = lo;  // first index with batch > t
    }
    __syncthreads();
    if (t < 64) {
        int gi = t;
        int lb = gi ? sub[gi - 1] : 0;
        int cnt = sub[gi] - lb;
        float inv = 1.0f / fmaxf((float)cnt, 1.0f);
        float a0 = 0.f, a1 = 0.f;
#pragma unroll 8
        for (int f = 0; f < 64; ++f) {
            float p = sp[gi * 65 + f];
            a0 = fmaf(p, Wc[f * 2 + 0], a0);
            a1 = fmaf(p, Wc[f * 2 + 1], a1);
        }
        out[gi * 2 + 0] = a0 * inv + bc[0];
        out[gi * 2 + 1] = a1 * inv + bc[1];
    }
}

extern "C" void kernel_launch(void* const* d_in, const int* in_sizes, int n_in,
                              void* d_out, int out_size, void* d_ws, size_t ws_size,
                              hipStream_t stream) {
    const float* x    = (const float*)d_in[0];
    const int*   ei   = (const int*)d_in[1];
    const int*   batch= (const int*)d_in[2];
    const float* W1 = (const float*)d_in[3];
    const float* b1 = (const float*)d_in[4];
    const float* g1 = (const float*)d_in[5];
    const float* be1= (const float*)d_in[6];
    const float* m1 = (const float*)d_in[7];
    const float* v1 = (const float*)d_in[8];
    const float* W2 = (const float*)d_in[9];
    const float* b2 = (const float*)d_in[10];
    const float* g2 = (const float*)d_in[11];
    const float* be2= (const float*)d_in[12];
    const float* m2 = (const float*)d_in[13];
    const float* v2 = (const float*)d_in[14];
    const float* Wc = (const float*)d_in[15];
    const float* bc = (const float*)d_in[16];
    float* out = (float*)d_out;

    char* ws = (char*)d_ws;
    size_t off = 0;
    auto alloc = [&](size_t bytes) {
        size_t o = off;
        off = (off + bytes + 511) & ~(size_t)511;
        return o;
    };
    size_t o_deg   = alloc((size_t)N_NODES_C * 4);
    size_t o_pool  = alloc((size_t)NUM_GRAPHS_C * D_C * 4);
    size_t zero_bytes = off;  // [deg | pooled] zeroed each call
    size_t o_rowptr= alloc((size_t)(N_NODES_C + 1) * 4);
    size_t o_cur   = alloc((size_t)N_NODES_C * 4);
    size_t o_dinv  = alloc((size_t)N_NODES_C * 4);
    size_t o_bsum  = alloc(128 * 4);
    size_t o_bscan = alloc(128 * 4);
    size_t o_colw  = alloc((size_t)N_EDGES_C * 8);
    size_t o_t     = alloc((size_t)N_NODES_C * D_C * 2);  // bf16
    size_t o_a     = alloc((size_t)N_NODES_C * D_C * 4);
    (void)ws_size; (void)in_sizes; (void)n_in; (void)out_size;

    int*   deg    = (int*)(ws + o_deg);
    float* pooled = (float*)(ws + o_pool);
    int*   rowptr = (int*)(ws + o_rowptr);
    int*   cursor = (int*)(ws + o_cur);
    float* dinv   = (float*)(ws + o_dinv);
    int*   bsum   = (int*)(ws + o_bsum);
    int*   bscan  = (int*)(ws + o_bscan);
    int2*  colw   = (int2*)(ws + o_colw);
    u16*   T      = (u16*)(ws + o_t);
    float* A      = (float*)(ws + o_a);

    const int* srcp = ei;
    const int* dstp = ei + N_EDGES_C;

    hipMemsetAsync(ws, 0, zero_bytes, stream);

    int eblocks = (N_EDGES_C + 255) / 256;
    int nb = (N_NODES_C + 1023) / 1024;  // 98
    int gblocks = 2048;  // 8192 persistent waves
    k_deg<<<eblocks, 256, 0, stream>>>(dstp, deg);
    k_scan_a<<<nb, 256, 0, stream>>>(deg, bsum);
    k_scan_b<<<1, 128, 0, stream>>>(bsum, bscan, nb);
    k_scan_c<<<nb, 256, 0, stream>>>(deg, bscan, rowptr, cursor, dinv);
    k_scatter<<<eblocks, 256, 0, stream>>>(srcp, dstp, cursor, dinv, colw);

    k_gemm64<<<2048, 256, 0, stream>>>(x, W1, T);
    k_gather1<<<gblocks, 256, 0, stream>>>(T, colw, rowptr, dinv, b1, g1, be1, m1, v1, A);
    k_gemm64<<<2048, 256, 0, stream>>>(A, W2, T);
    k_gather2<<<gblocks, 256, 0, stream>>>(T, colw, rowptr, dinv, b2, g2, be2, m2, v2,
                                           batch, pooled);
    k_final<<<1, 256, 0, stream>>>(pooled, batch, Wc, bc, out);
}